// Round 3
// baseline (252.822 us; speedup 1.0000x reference)
//
#include <hip/hip_runtime.h>
#include <hip/hip_bf16.h>

// HypConvHyperboloid: B=32,H=64,W=64, C_IN=65, 3x3 edge-pad conv -> HCat(577) -> Lorentz FC(255) -> time restore
// M = 131072 pixels, K = 576 (bf16 MFMA) + 1 (t_cat fp32 rank-1 in epilogue), N = 255 (pad 256)
// Round 8: R5/R7 showed the invariant cost is the per-iteration barrier drain vs tiny BK=32 compute
//          (~16 MFMA/wave per barrier ~ load latency -> stall every iter, regardless of domain count).
//          Fix: keep the PROVEN minimum-2-phase schedule, scale compute-per-barrier 4x:
//          BM=256 x BN=256(full N) x BK=64, 8 waves (128x64 each, acc 128 regs), 9 iters.
//          K-order k = nbr*64 + c: one BK-step = one neighbor, contiguous 128B/pixel staging.
//          Slot-major LDS (R5's conflict-free layout) at 128KB dbuf -> 1 block/CU.
//          Full-N block restores single-kernel row sum: finalize_t + ssbuf DELETED.

#define CLAMP63(v) ((v) < 0 ? 0 : ((v) > 63 ? 63 : (v)))

typedef __attribute__((ext_vector_type(8))) short short8;   // 8 bf16 = 4 VGPRs
typedef __attribute__((ext_vector_type(4))) float floatx4;  // C/D frag

__device__ __forceinline__ void gl2lds16(const void* g, void* l) {
  __builtin_amdgcn_global_load_lds(
      (const __attribute__((address_space(1))) void*)g,
      (__attribute__((address_space(3))) void*)l, 16, 0, 0);
}

// ---- merged prep: blocks [0,4096): x spatial -> bf16 pixel-major [pix][64]; col0 -> tsq = t^2
//                   blocks [4096,4352): W -> bf16 n-major [256][576] with row 0 ZERO (n^ = out col),
//                                       W col0 + b -> fp32 padded (entry 0 zero)
__global__ void prep(const float* __restrict__ x, const float* __restrict__ W,
                     const float* __restrict__ b,
                     __hip_bfloat16* __restrict__ xs, float* __restrict__ tsq,
                     __hip_bfloat16* __restrict__ Wb, float* __restrict__ Wt0,
                     float* __restrict__ bp) {
  if (blockIdx.x < 4096) {
    int idx = blockIdx.x * 256 + threadIdx.x;   // 1048576 = 131072 pix * 8 groups
    int p = idx >> 3, g = idx & 7;
    const float* src = x + (size_t)p * 65 + 1 + g * 8;
    __align__(16) __hip_bfloat16 tmp[8];
#pragma unroll
    for (int i = 0; i < 8; ++i) tmp[i] = __float2bfloat16(src[i]);
    *(short8*)(xs + (size_t)idx * 8) = *(const short8*)tmp;
    if (g == 0) { float t = x[(size_t)p * 65]; tsq[p] = t * t; }
  } else {
    int n = blockIdx.x - 4096;  // n^ in 0..255; n^>=1 maps to W row n^-1
    for (int k = threadIdx.x; k < 576; k += 256)
      Wb[n * 576 + k] = __float2bfloat16((n >= 1) ? W[(n - 1) * 577 + 1 + k] : 0.f);
    if (threadIdx.x == 0) {
      Wt0[n] = (n >= 1) ? W[(n - 1) * 577] : 0.f;
      bp[n]  = (n >= 1) ? b[n - 1] : 0.f;
    }
  }
}

// staging for K-step IT (= neighbor index, 0..8), buffer BUF.
// Per thread: 4 A + 4 B gl2lds. Slot s = r*512 + tid; kg = s>>8 = 2r + (w>>2); col idx = s&255.
// A src: xs[pixel(sm)][kg*8..], contiguous 128B/pixel row. B src: Wb[sm][IT*64 + kg*8 ..].
// LDS dest linear: ushort offset r*4096 + w*512 (+ lane*8 by HW). Conflict-free slot-major layout.
#define STAGE(IT, BUF)                                                           \
  do {                                                                           \
    const int dy_ = (IT) / 3 - 1, dx_ = (IT) % 3 - 1;                            \
    int y2_ = CLAMP63(a_by + dy_);                                               \
    int x2_ = CLAMP63(a_bx + dx_);                                               \
    const __hip_bfloat16* asrc_ = xs + (size_t)((a_bb * 64 + y2_) * 64 + x2_) * 64; \
    _Pragma("unroll")                                                            \
    for (int r_ = 0; r_ < 4; ++r_) {                                             \
      const int kg_ = 2 * r_ + kg_lo;                                            \
      gl2lds16(asrc_ + kg_ * 8, Ab + (BUF) * 16384 + r_ * 4096 + w * 512);       \
      gl2lds16(b_base + (IT) * 64 + kg_ * 8, Bb + (BUF) * 16384 + r_ * 4096 + w * 512); \
    }                                                                            \
  } while (0)

// ---- main: M=256 x N=256 per block, BK=64, 9 iters, 8 waves (each 128x64), dbuf LDS (2-phase,
// compiler-scheduled). 129KB LDS -> 1 block/CU, 8 waves (2/SIMD).
__launch_bounds__(512, 2)
__global__ void hypconv_main(const float* __restrict__ tsq,
                             const __hip_bfloat16* __restrict__ xs,
                             const __hip_bfloat16* __restrict__ Wb,
                             const float* __restrict__ Wt0,
                             const float* __restrict__ bp,
                             float* __restrict__ out) {
  __shared__ __align__(16) char smem[131072];  // A dbuf 64K + B dbuf 64K; reused: zbuf 32 x 260 f32
  __shared__ float tc_lds[256];
  ushort* Ab = (ushort*)smem;                  // 2 x 16384 ushort
  ushort* Bb = (ushort*)(smem + 65536);        // 2 x 16384 ushort
  float* zbuf = (float*)smem;                  // 32 rows x 260 f32 = 33280 B

  const int tid = threadIdx.x;
  const int w = tid >> 6, lane = tid & 63;
  const int quad = lane >> 4, ln = lane & 15;

  // XCD swizzle: 512 blocks, 64-chunk per XCD (bijective, 512%8==0)
  const int mb = ((blockIdx.x & 7) << 6) + (blockIdx.x >> 3);
  const int pix_base = mb * 256;
  const int wr = w >> 2, wc = w & 3;
  const int m_off = wr * 128, n_off = wc * 64;

  // staging constants: sm = column index (A pixel-row / B n-row), kg_lo = kg parity half
  const int sm = (w & 3) * 64 + lane;
  const int kg_lo = w >> 2;
  const int apix = pix_base + sm;
  const int a_bx = apix & 63, a_by = (apix >> 6) & 63, a_bb = apix >> 12;
  const __hip_bfloat16* b_base = Wb + (size_t)sm * 576;

  floatx4 acc[8][4];
#pragma unroll
  for (int mf = 0; mf < 8; ++mf)
#pragma unroll
    for (int nf = 0; nf < 4; ++nf)
      acc[mf][nf] = (floatx4){0.f, 0.f, 0.f, 0.f};

  // t_cat (tsq 512KB, L2-resident): 256 rows of this block
  if (tid < 256) {
    int pix = pix_base + tid;
    int bx = pix & 63, by = (pix >> 6) & 63, bb = pix >> 12;
    float s = 0.f;
#pragma unroll
    for (int dy = -1; dy <= 1; ++dy) {
      int y2 = CLAMP63(by + dy);
#pragma unroll
      for (int dx = -1; dx <= 1; ++dx) {
        int x2 = CLAMP63(bx + dx);
        s += tsq[(bb * 64 + y2) * 64 + x2];
      }
    }
    tc_lds[tid] = sqrtf(s - 8.0f);
  }

  STAGE(0, 0);  // prologue loads in flight

#pragma unroll
  for (int it = 0; it < 9; ++it) {
    __syncthreads();                 // buf(it&1) ready; prev frag reads done
    if (it < 8) STAGE(it + 1, (it + 1) & 1);   // prefetch overlaps frag reads + MFMA
    const ushort* Ar = Ab + (it & 1) * 16384;
    const ushort* Br = Bb + (it & 1) * 16384;
#pragma unroll
    for (int ks = 0; ks < 2; ++ks) {
      short8 af[8], bfr[4];
#pragma unroll
      for (int mf = 0; mf < 8; ++mf)
        af[mf] = *(const short8*)&Ar[((ks * 4 + quad) * 256 + m_off + mf * 16 + ln) * 8];
#pragma unroll
      for (int nf = 0; nf < 4; ++nf)
        bfr[nf] = *(const short8*)&Br[((ks * 4 + quad) * 256 + n_off + nf * 16 + ln) * 8];
#pragma unroll
      for (int mf = 0; mf < 8; ++mf)
#pragma unroll
        for (int nf = 0; nf < 4; ++nf)
          acc[mf][nf] = __builtin_amdgcn_mfma_f32_16x16x32_bf16(af[mf], bfr[nf], acc[mf][nf], 0, 0, 0);
    }
  }

  // ---- epilogue: z = acc + b[n^] + t_cat[m]*W0[n^]; LDS-staged (stride 260), full-row sum in block.
  // GEMM col 0 has zero weights -> z[0]=0; t_out overwrites col 0 at flush. 8 chunks of 32 rows.
  __syncthreads();
  float wn[4], bnv[4];
#pragma unroll
  for (int nf = 0; nf < 4; ++nf) {
    int n = n_off + nf * 16 + ln;
    wn[nf] = Wt0[n];
    bnv[nf] = bp[n];
  }

#pragma unroll
  for (int mf = 0; mf < 8; ++mf) {
    // stage 32 rows: lr = wr*16 + quad*4 + r ; col = n_off + nf*16 + ln (0..255)
#pragma unroll
    for (int r = 0; r < 4; ++r) {
      float tcv = tc_lds[m_off + mf * 16 + quad * 4 + r];
      int lr = wr * 16 + quad * 4 + r;
#pragma unroll
      for (int nf = 0; nf < 4; ++nf) {
        float z = acc[mf][nf][r] + bnv[nf] + tcv * wn[nf];
        zbuf[lr * 260 + n_off + nf * 16 + ln] = z;
      }
    }
    __syncthreads();
    // flush: 8 waves x 4 rows; sum(z^2) 64-lane butterfly; t_out -> col 0
#pragma unroll
    for (int rr = 0; rr < 4; ++rr) {
      int lr = w * 4 + rr;
      float4 v = *(const float4*)&zbuf[lr * 260 + lane * 4];
      float ss = v.x * v.x + v.y * v.y + v.z * v.z + v.w * v.w;  // col0 holds z[0]=0
      ss += __shfl_xor(ss, 1, 64);
      ss += __shfl_xor(ss, 2, 64);
      ss += __shfl_xor(ss, 4, 64);
      ss += __shfl_xor(ss, 8, 64);
      ss += __shfl_xor(ss, 16, 64);
      ss += __shfl_xor(ss, 32, 64);
      float tout = sqrtf(1.0f + ss);
      if (lane == 0) v.x = tout;
      int m = (lr >> 4) * 128 + mf * 16 + (lr & 15);
      *(float4*)&out[(size_t)(pix_base + m) * 256 + lane * 4] = v;
    }
    if (mf < 7) __syncthreads();  // protect zbuf before next chunk's staging
  }
}

extern "C" void kernel_launch(void* const* d_in, const int* in_sizes, int n_in,
                              void* d_out, int out_size, void* d_ws, size_t ws_size,
                              hipStream_t stream) {
  const float* x = (const float*)d_in[0];   // (32,64,64,65)
  const float* W = (const float*)d_in[1];   // (255,577)
  const float* b = (const float*)d_in[2];   // (255,)
  float* out = (float*)d_out;               // (32,64,64,256)
  char* ws = (char*)d_ws;

  // workspace: xs 16,777,216 | Wb 294,912 | Wt0 1K | bp 1K | tsq 524,288  (~17.6 MB)
  __hip_bfloat16* xs  = (__hip_bfloat16*)(ws);
  __hip_bfloat16* Wb  = (__hip_bfloat16*)(ws + 16777216);
  float*          Wt0 = (float*)(ws + 17072128);
  float*          bp  = (float*)(ws + 17073152);
  float*          tsq = (float*)(ws + 17074176);

  prep<<<4352, 256, 0, stream>>>(x, W, b, xs, tsq, Wb, Wt0, bp);
  hypconv_main<<<512, 512, 0, stream>>>(tsq, xs, Wb, Wt0, bp, out);
}

// Round 4
// 231.868 us; speedup vs baseline: 1.0904x; 1.0904x over previous
//
#include <hip/hip_runtime.h>
#include <hip/hip_bf16.h>

// HypConvHyperboloid: B=32,H=64,W=64, C_IN=65, 3x3 edge-pad conv -> HCat(577) -> Lorentz FC(255) -> time restore
// M = 131072 pixels, K = 576 (bf16 MFMA) + 1 (t_cat fp32 rank-1 in epilogue), N = 255 (pad 256)
// Round 9: FUSED. R5's schedule/geometry (128x256, BK=32, 8 waves, 2 blocks/CU) was best; restructures
//          (R6 counted-vmcnt, R7 4-domain, R8 256^2) all lost. total-main is a constant ~130us -> attack
//          prep_x + main's staging latency together: per-block 4x66 clamped-halo pixel cache in LDS
//          (bf16 [pix][64], XOR-swizzled chunk^=pix&7 -> conflict-free stride-128B fragment gathers).
//          A-staging, xs workspace (16.7MB RW), tsq, and prep_x are DELETED. K-loop barrier drain now
//          covers only 2 L2-hot B gl2lds per wave. t^2 free from the same halo rows. Epilogue = R5 zbuf
//          butterfly + R8 col0-zero mapping (aligned f4 stores, t_out in-kernel).

#define CLAMP63(v) ((v) < 0 ? 0 : ((v) > 63 ? 63 : (v)))

typedef __attribute__((ext_vector_type(8))) short short8;   // 8 bf16 = 4 VGPRs
typedef __attribute__((ext_vector_type(4))) float floatx4;  // C/D frag

__device__ __forceinline__ void gl2lds16(const void* g, void* l) {
  __builtin_amdgcn_global_load_lds(
      (const __attribute__((address_space(1))) void*)g,
      (__attribute__((address_space(3))) void*)l, 16, 0, 0);
}

// ---- prep: W -> bf16 n-major [256][576] with row 0 ZERO (GEMM col n^ == out col n^);
//            W col0 + b -> fp32 padded (entry 0 zero)
__global__ void prep_w(const float* __restrict__ W, const float* __restrict__ b,
                       __hip_bfloat16* __restrict__ Wb, float* __restrict__ Wt0,
                       float* __restrict__ bp) {
  int n = blockIdx.x;  // n^ in 0..255; n^>=1 maps to W row n^-1
  for (int k = threadIdx.x; k < 576; k += 256)
    Wb[n * 576 + k] = __float2bfloat16((n >= 1) ? W[(n - 1) * 577 + 1 + k] : 0.f);
  if (threadIdx.x == 0) {
    Wt0[n] = (n >= 1) ? W[(n - 1) * 577] : 0.f;
    bp[n]  = (n >= 1) ? b[n - 1] : 0.f;
  }
}

// B staging for K-step IT (0..17), buffer BUF: 2 chunks/wave, dests wave-uniform (R5-proven, 0 conflicts)
#define STAGE_B(IT, BUF)                                                          \
  do {                                                                            \
    _Pragma("unroll")                                                             \
    for (int j_ = 0; j_ < 2; ++j_)                                                \
      gl2lds16(b_src[j_] + (IT) * 32, Bb + (BUF) * 8192 + (w * 2 + j_) * 512);    \
  } while (0)

// ---- main: M=128 x N=256 per block, BK=32, 18 iters, 8 waves (each 64x64), fused halo pixel-cache.
// LDS: pc [0,33792) 4x66 pixels x 128B (XOR-swizzled) | ts [33792,34848) 4x66 f32 t^2
//      Bb [34848,67616) dbuf 2x16KB | zbuf (epilogue) reuses [0,33280).
__launch_bounds__(512, 2)
__global__ void hypconv_main(const float* __restrict__ x,
                             const __hip_bfloat16* __restrict__ Wb,
                             const float* __restrict__ Wt0,
                             const float* __restrict__ bp,
                             float* __restrict__ out) {
  __shared__ __align__(16) char smem[67616];
  __shared__ float tc_lds[128];
  float* ts = (float*)(smem + 33792);
  ushort* Bb = (ushort*)(smem + 34848);
  float* zbuf = (float*)smem;

  const int tid = threadIdx.x;
  const int w = tid >> 6, lane = tid & 63;
  const int quad = lane >> 4, ln = lane & 15;

  // XCD swizzle: 1024 blocks, 128-chunk per XCD (bijective); adjacent mb share halo rows + Wb in L2
  const int mb = ((blockIdx.x & 7) << 7) + (blockIdx.x >> 3);
  const int pix_base = mb * 128;
  const int bb = mb >> 5;                 // image index (4096 pix/image, 128 pix/block)
  const int r0 = (mb & 31) << 1;          // first of the block's 2 image rows
  const int m_off = (w >> 2) * 64, n_off = (w & 3) * 64;

  // B chunks j=0,1: slot = (w*2+j)*64+lane -> kg = slot>>8? (R5 mapping: kg=(c>>2), n=(c&3)*64+lane)
  const __hip_bfloat16* b_src[2];
#pragma unroll
  for (int j = 0; j < 2; ++j) {
    int c = w * 2 + j;
    b_src[j] = Wb + (size_t)((c & 3) * 64 + lane) * 576 + (c >> 2) * 8;
  }

  floatx4 acc[4][4];
#pragma unroll
  for (int mf = 0; mf < 4; ++mf)
#pragma unroll
    for (int nf = 0; nf < 4; ++nf)
      acc[mf][nf] = (floatx4){0.f, 0.f, 0.f, 0.f};

  STAGE_B(0, 0);  // B prologue loads overlap the halo staging below

  // ---- halo pixel cache (once): 4 rows x 66 cols, clamped; bf16 [pix][64] chunk-swizzled; ts = t^2
  for (int t = tid; t < 528; t += 512) {
    const int hp = t >> 1, h = t & 1;           // pixel, channel-half
    const int hyi = hp / 66, hxj = hp - hyi * 66;
    const int gy = CLAMP63(r0 - 1 + hyi);
    const int gx = CLAMP63(hxj - 1);
    const float* row = x + (size_t)((bb << 12) + (gy << 6) + gx) * 65;
    if (h == 0) { float tv = row[0]; ts[hp] = tv * tv; }
    const float* sp = row + 1 + h * 32;         // channels h*32 .. h*32+31
#pragma unroll
    for (int q = 0; q < 4; ++q) {
      const int cg = h * 4 + q;                 // 8-channel group 0..7
      __align__(16) __hip_bfloat16 tmp[8];
#pragma unroll
      for (int i = 0; i < 8; ++i) tmp[i] = __float2bfloat16(sp[q * 8 + i]);
      *(short8*)(smem + hp * 128 + ((cg ^ (hp & 7)) << 4)) = *(const short8*)tmp;
    }
  }
  __syncthreads();

  // t_cat for the block's 128 pixels (reads clamped t^2 from halo)
  if (tid < 128) {
    const int ri = tid >> 6, cm = tid & 63;
    float s = 0.f;
#pragma unroll
    for (int i = 0; i < 3; ++i)
#pragma unroll
      for (int j = 0; j < 3; ++j)
        s += ts[(ri + i) * 66 + cm + j];
    tc_lds[tid] = sqrtf(s - 8.0f);
  }

  // ---- K-loop: 18 x BK=32. A frags direct from pixel cache (no staging, no barrier dep);
  // B double-buffered gl2lds (2 loads/wave in the drain). R5 2-phase schedule, compiler-scheduled.
  const int rowterm = (1 + (w >> 2)) * 66 + 1 + ln;  // halo pix at (dy=0,dx=0,mf=0)
#pragma unroll
  for (int it = 0; it < 18; ++it) {
    __syncthreads();                 // Bb(it&1) ready; prev frag reads done
    if (it < 17) STAGE_B(it + 1, (it + 1) & 1);
    const int nbr = it >> 1;
    const int dy = nbr / 3 - 1, dx = nbr % 3 - 1;
    const int c4 = (it & 1) * 4 + quad;          // 8-channel group for this frag
    const int pb = rowterm + dy * 66 + dx;
    const ushort* Br = Bb + (it & 1) * 8192;
    short8 af[4], bfr[4];
#pragma unroll
    for (int mf = 0; mf < 4; ++mf) {
      const int pix = pb + mf * 16;
      af[mf] = *(const short8*)(smem + pix * 128 + ((c4 ^ (pix & 7)) << 4));
    }
#pragma unroll
    for (int nf = 0; nf < 4; ++nf)
      bfr[nf] = *(const short8*)&Br[(quad * 256 + n_off + nf * 16 + ln) * 8];
#pragma unroll
    for (int mf = 0; mf < 4; ++mf)
#pragma unroll
      for (int nf = 0; nf < 4; ++nf)
        acc[mf][nf] = __builtin_amdgcn_mfma_f32_16x16x32_bf16(af[mf], bfr[nf], acc[mf][nf], 0, 0, 0);
  }

  // ---- epilogue: z = acc + b[n^] + t_cat[m]*W0[n^]; zbuf stride 260 (conflict-free, R5);
  // col n^=0 is exactly 0 (zero weight row) -> aligned f4 stores, t_out overwrites col 0.
  __syncthreads();
  float wn[4], bnv[4];
#pragma unroll
  for (int nf = 0; nf < 4; ++nf) {
    int n = n_off + nf * 16 + ln;
    wn[nf] = Wt0[n];
    bnv[nf] = bp[n];
  }

#pragma unroll
  for (int mf = 0; mf < 4; ++mf) {
    // stage 32 rows: lr = (w>>2)*16 + quad*4 + r ; col = n_off + nf*16 + ln (0..255)
#pragma unroll
    for (int r = 0; r < 4; ++r) {
      float tcv = tc_lds[m_off + mf * 16 + quad * 4 + r];
      int lr = (w >> 2) * 16 + quad * 4 + r;
#pragma unroll
      for (int nf = 0; nf < 4; ++nf) {
        float z = acc[mf][nf][r] + bnv[nf] + tcv * wn[nf];
        zbuf[lr * 260 + n_off + nf * 16 + ln] = z;
      }
    }
    __syncthreads();
    // flush: 8 waves x 4 rows; sum(z^2) 64-lane butterfly; t_out -> col 0
#pragma unroll
    for (int rr = 0; rr < 4; ++rr) {
      int lr = w * 4 + rr;
      float4 v = *(const float4*)&zbuf[lr * 260 + lane * 4];
      float ss = v.x * v.x + v.y * v.y + v.z * v.z + v.w * v.w;  // col0 holds 0
      ss += __shfl_xor(ss, 1, 64);
      ss += __shfl_xor(ss, 2, 64);
      ss += __shfl_xor(ss, 4, 64);
      ss += __shfl_xor(ss, 8, 64);
      ss += __shfl_xor(ss, 16, 64);
      ss += __shfl_xor(ss, 32, 64);
      float tout = sqrtf(1.0f + ss);
      if (lane == 0) v.x = tout;
      int m = (lr >> 4) * 64 + mf * 16 + (lr & 15);
      *(float4*)&out[(size_t)(pix_base + m) * 256 + lane * 4] = v;
    }
    if (mf < 3) __syncthreads();  // protect zbuf before next chunk's staging
  }
}

extern "C" void kernel_launch(void* const* d_in, const int* in_sizes, int n_in,
                              void* d_out, int out_size, void* d_ws, size_t ws_size,
                              hipStream_t stream) {
  const float* x = (const float*)d_in[0];   // (32,64,64,65)
  const float* W = (const float*)d_in[1];   // (255,577)
  const float* b = (const float*)d_in[2];   // (255,)
  float* out = (float*)d_out;               // (32,64,64,256)
  char* ws = (char*)d_ws;

  // workspace: Wb 294,912 | Wt0 1K | bp 1K  (~0.3 MB; xs/tsq deleted)
  __hip_bfloat16* Wb  = (__hip_bfloat16*)(ws);
  float*          Wt0 = (float*)(ws + 294912);
  float*          bp  = (float*)(ws + 295936);

  prep_w<<<256, 256, 0, stream>>>(W, b, Wb, Wt0, bp);
  hypconv_main<<<1024, 512, 0, stream>>>(x, Wb, Wt0, bp, out);
}